// Round 11
// baseline (417.485 us; speedup 1.0000x reference)
//
#include <hip/hip_runtime.h>
#include <hip/hip_bf16.h>
#include <math.h>

#define NSEG 25000
#define NPTS 500000
#define S_RFF 0.08838834764831845f      // sqrt(2/256)
#define INV2PI 0.15915494309189535f     // 1/(2*pi)
#define C_EXP2 (-0.7213475204444817f)   // -0.5*log2(e)

typedef __attribute__((ext_vector_type(8))) short v8s;
typedef __attribute__((ext_vector_type(4))) float v4f;

#define MF(a,b,c) __builtin_amdgcn_mfma_f32_16x16x32_bf16(a,b,c,0,0,0)

// ---- d_ws plane offsets (fragment order; constants folded at prep) ----
#define W1 0          // (Om0/2pi)^T [mt 16][kcg 2][pl 2(hi,lo)] x 1KB = 64KB  (no pi)
#define W2 65536      // (S*Wm0)^T   [kc 8][mt 8][pl 2(hi, S^2*E)] x 1KB = 128KB (pi)
#define W3 196608     // (Om1/2pi)^T [kc 4][mt 16][pl 2(hi, C*Om1^2)] x 1KB = 128KB (pi)
#define W4 327680     // (S*Wm1)     [kc 8][dt 4][pl 2(hi, S^2*E)] x 1KB = 64KB (pi, B-frag)
#define B0P 393216    // b0/2pi, 256 floats
#define B1P 394240    // b1/2pi, 256 floats
// total ~386KB, fully L2-resident

__device__ __forceinline__ ushort bf16_rne(float f) {
    uint u = __builtin_bit_cast(uint, f);
    u += 0x7fffu + ((u >> 16) & 1u);
    return (ushort)(u >> 16);
}
__device__ __forceinline__ float bf16f(ushort h) {
    uint u = ((uint)h) << 16;
    return __builtin_bit_cast(float, u);
}
__device__ __forceinline__ uint pk2(float a, float b) {
    __hip_bfloat162 h = __float22bfloat162_rn(make_float2(a, b));
    union { __hip_bfloat162 h; uint u; } c; c.h = h; return c.u;
}
__device__ __forceinline__ v8s mk8(uint a, uint b, uint c, uint d) {
    union { uint u[4]; v8s v; } x; x.u[0]=a; x.u[1]=b; x.u[2]=c; x.u[3]=d; return x.v;
}
__device__ __forceinline__ void unpk2(uint u, float& a, float& b) {
    a = __builtin_bit_cast(float, u << 16);
    b = __builtin_bit_cast(float, u & 0xffff0000u);
}
// cos with argument in revolutions: v_fract + v_cos (2 instructions)
__device__ __forceinline__ float cosr(float x) {
    return __builtin_amdgcn_cosf(__builtin_amdgcn_fractf(x));
}

// slot position for k-permuted frags: far side provides k = 4g+j (j<4) / 16+4g+(j-4)
__device__ __forceinline__ int pi_el(int k32, int row) {
    int gk, j;
    if (k32 < 16) { gk = k32 >> 2; j = k32 & 3; }
    else          { gk = (k32 - 16) >> 2; j = 4 + ((k32 - 16) & 3); }
    return (gk * 16 + row) * 8 + j;
}

// ---------- prep: weights -> fragment planes with folded constants (unchanged) ----------
__global__ void dgp_prep(const float* __restrict__ Om0, const float* __restrict__ Wm0,
                         const float* __restrict__ Wlv0, const float* __restrict__ Om1,
                         const float* __restrict__ Wm1, const float* __restrict__ Wlv1,
                         const float* __restrict__ b0, const float* __restrict__ b1,
                         char* __restrict__ ws)
{
    const int idx = blockIdx.x * 256 + threadIdx.x;   // 0..32767
    if (idx < 16384) {   // W1: (Om0/2pi) hi/lo (3-term G1 kept)
        int k = idx >> 8, c = idx & 255;
        int kcg = k >> 5, k32 = k & 31, mt = c >> 4, row = c & 15;
        int el = ((k32 >> 3) * 16 + row) * 8 + (k32 & 7);
        float v = Om0[idx] * INV2PI;
        ushort hi = bf16_rne(v), lo = bf16_rne(v - bf16f(hi));
        ushort* p = (ushort*)(ws + W1);
        int t0 = (mt * 2 + kcg) * 2;
        p[(size_t)t0 * 512 + el] = hi;
        p[(size_t)(t0 + 1) * 512 + el] = lo;
    }
    {   // W2: S*Wm0 + S^2*exp(Wlv0), single-term, pi
        int k = idx >> 7, n = idx & 127;
        int kc = k >> 5, k32 = k & 31, mt = n >> 4, row = n & 15;
        int el = pi_el(k32, row);
        ushort* p = (ushort*)(ws + W2);
        int t0 = (kc * 8 + mt) * 2;
        p[(size_t)t0 * 512 + el] = bf16_rne(S_RFF * Wm0[idx]);
        p[(size_t)(t0 + 1) * 512 + el] = bf16_rne(S_RFF * S_RFF * expf(Wlv0[idx]));
    }
    {   // W3: Om1/2pi + (-0.5*log2e)*Om1^2, single-term, pi
        int k = idx >> 8, c = idx & 255;
        int kc = k >> 5, k32 = k & 31, mt = c >> 4, row = c & 15;
        int el = pi_el(k32, row);
        float v = Om1[idx];
        ushort* p = (ushort*)(ws + W3);
        int t0 = (kc * 16 + mt) * 2;
        p[(size_t)t0 * 512 + el] = bf16_rne(v * INV2PI);
        p[(size_t)(t0 + 1) * 512 + el] = bf16_rne(C_EXP2 * v * v);
    }
    if (idx < 16384) {   // W4: S*Wm1 + S^2*exp(Wlv1), pi (B-frag)
        int k = idx >> 6, d = idx & 63;
        int kc = k >> 5, k32 = k & 31, dt = d >> 4, row = d & 15;
        int el = pi_el(k32, row);
        ushort* p = (ushort*)(ws + W4);
        int t0 = (kc * 4 + dt) * 2;
        p[(size_t)t0 * 512 + el] = bf16_rne(S_RFF * Wm1[idx]);
        p[(size_t)(t0 + 1) * 512 + el] = bf16_rne(S_RFF * S_RFF * expf(Wlv1[idx]));
    }
    if (idx < 256) ((float*)(ws + B0P))[idx] = b0[idx] * INV2PI;
    if (idx < 256) ((float*)(ws + B1P))[idx] = b1[idx] * INV2PI;
}

// ---------- whole-plane staging (global -> LDS, linear, 16B/lane, 8 waves) ----------
typedef __attribute__((address_space(1))) const unsigned int g_u32;
typedef __attribute__((address_space(3))) unsigned int l_u32;

__device__ __forceinline__ void stage_plane128(const char* gsrc, char* dst, int w, int l) {
    #pragma unroll
    for (int i = 0; i < 16; ++i) {
        const int idx = i * 8 + w;   // 128 x 1KB fragments, 8 waves
        __builtin_amdgcn_global_load_lds((g_u32*)(gsrc + idx * 1024 + l * 16),
                                         (l_u32*)(dst + idx * 1024), 16, 0, 0);
    }
}

// ---------- fused main: 8 waves x 32 pts; whole W2/W3 plane in LDS; 3 barriers total ----------
__global__ __launch_bounds__(512, 2)
void dgp_main(const float* __restrict__ x, const int* __restrict__ xidx,
              const float* __restrict__ b0, const float* __restrict__ b1,
              const char* __restrict__ ws,
              float* __restrict__ sum_wm, float* __restrict__ sum_inv)
{
    __shared__ __attribute__((aligned(16))) char lds[131072];   // one 128KB plane
    const int t = threadIdx.x, l = t & 63, w = t >> 6;          // w 0..7
    const int r16 = l & 15, g = l >> 4;
    const int base = blockIdx.x * 256 + w * 32;

    const v4f zf = {0.f, 0.f, 0.f, 0.f};

    // stage W2 plane (128KB) while x loads are in flight
    stage_plane128(ws + W2, lds, w, l);

    // ---- x B-frags (hi/lo, 2 sets x 2 K-chunks) ----
    v8s xh[2][2], xl[2][2];
    #pragma unroll
    for (int st = 0; st < 2; ++st) {
        const int pc = min(base + st * 16 + r16, NPTS - 1);
        #pragma unroll
        for (int kcg = 0; kcg < 2; ++kcg) {
            const float* xp = x + (size_t)pc * 64 + kcg * 32 + g * 8;
            float4 a = *(const float4*)xp;
            float4 b = *(const float4*)(xp + 4);
            uint h0 = pk2(a.x, a.y), h1 = pk2(a.z, a.w), h2 = pk2(b.x, b.y), h3 = pk2(b.z, b.w);
            float q0,q1,q2,q3,q4,q5,q6,q7;
            unpk2(h0,q0,q1); unpk2(h1,q2,q3); unpk2(h2,q4,q5); unpk2(h3,q6,q7);
            xh[st][kcg] = mk8(h0, h1, h2, h3);
            xl[st][kcg] = mk8(pk2(a.x-q0, a.y-q1), pk2(a.z-q2, a.w-q3),
                              pk2(b.x-q4, b.y-q5), pk2(b.z-q6, b.w-q7));
        }
    }

    v4f am[2][8], av[2][8];
    #pragma unroll
    for (int st = 0; st < 2; ++st)
        #pragma unroll
        for (int nt = 0; nt < 8; ++nt) { am[st][nt] = zf; av[st][nt] = zf; }

    v4f zc[2][2] = {{zf, zf}, {zf, zf}};

    // G1: accumulate z'^T pair for tile-pair kc into z[set][tt] (3-term split product)
    auto G1 = [&](int kc, v4f z[2][2]) {
        #pragma unroll
        for (int tt = 0; tt < 2; ++tt) {
            const int mt = 2 * kc + tt;
            #pragma unroll
            for (int kcg = 0; kcg < 2; ++kcg) {
                const char* wp = ws + W1 + (size_t)((mt * 2 + kcg) * 2) * 1024 + l * 16;
                v8s ah = *(const v8s*)wp;
                v8s al = *(const v8s*)(wp + 1024);
                #pragma unroll
                for (int st = 0; st < 2; ++st) {
                    v4f a = z[st][tt];
                    a = MF(ah, xh[st][kcg], a);
                    a = MF(al, xh[st][kcg], a);
                    a = MF(ah, xl[st][kcg], a);
                    z[st][tt] = a;
                }
            }
        }
    };

    G1(0, zc);
    __syncthreads();   // W2 plane resident (barrier drains each wave's loads first)

    // ================= layer 0: 8 phases, barrier-free; G2 <- LDS =================
    auto phase0 = [&](int kc, bool dn) {
        v4f zn[2][2] = {{zf, zf}, {zf, zf}};
        if (dn) G1(kc + 1, zn);

        float4 bbA = *(const float4*)(b0 + (2 * kc) * 16 + 4 * g);
        float4 bbB = *(const float4*)(b0 + (2 * kc + 1) * 16 + 4 * g);
        v8s ph[2], psq[2];
        #pragma unroll
        for (int st = 0; st < 2; ++st) {
            float pA[4], pB[4];
            pA[0] = cosr(zc[st][0][0] + bbA.x);
            pA[1] = cosr(zc[st][0][1] + bbA.y);
            pA[2] = cosr(zc[st][0][2] + bbA.z);
            pA[3] = cosr(zc[st][0][3] + bbA.w);
            pB[0] = cosr(zc[st][1][0] + bbB.x);
            pB[1] = cosr(zc[st][1][1] + bbB.y);
            pB[2] = cosr(zc[st][1][2] + bbB.z);
            pB[3] = cosr(zc[st][1][3] + bbB.w);
            ph[st]  = mk8(pk2(pA[0], pA[1]), pk2(pA[2], pA[3]),
                          pk2(pB[0], pB[1]), pk2(pB[2], pB[3]));
            psq[st] = mk8(pk2(pA[0]*pA[0], pA[1]*pA[1]), pk2(pA[2]*pA[2], pA[3]*pA[3]),
                          pk2(pB[0]*pB[0], pB[1]*pB[1]), pk2(pB[2]*pB[2], pB[3]*pB[3]));
        }

        __builtin_amdgcn_s_setprio(1);
        #pragma unroll
        for (int nt = 0; nt < 8; ++nt) {
            const char* bp = lds + (size_t)((kc * 8 + nt) * 2) * 1024 + l * 16;
            v8s wh = *(const v8s*)bp;
            v8s we = *(const v8s*)(bp + 1024);
            #pragma unroll
            for (int st = 0; st < 2; ++st) {
                am[st][nt] = MF(wh, ph[st], am[st][nt]);
                av[st][nt] = MF(we, psq[st], av[st][nt]);
            }
        }
        __builtin_amdgcn_s_setprio(0);
        #pragma unroll
        for (int st = 0; st < 2; ++st) { zc[st][0] = zn[st][0]; zc[st][1] = zn[st][1]; }
    };

    for (int kc = 0; kc < 7; ++kc)
        phase0(kc, true);
    phase0(7, false);

    // ---- transition: m0/v0 accs -> B-frags (in-register pack) ----
    v8s m0B[2][4], v0B[2][4];
    #pragma unroll
    for (int st = 0; st < 2; ++st)
        #pragma unroll
        for (int kd = 0; kd < 4; ++kd) {
            v4f a0 = am[st][2 * kd], a1 = am[st][2 * kd + 1];
            v4f b0v = av[st][2 * kd], b1v = av[st][2 * kd + 1];
            m0B[st][kd] = mk8(pk2(a0[0], a0[1]), pk2(a0[2], a0[3]),
                              pk2(a1[0], a1[1]), pk2(a1[2], a1[3]));
            v0B[st][kd] = mk8(pk2(b0v[0], b0v[1]), pk2(b0v[2], b0v[3]),
                              pk2(b1v[0], b1v[1]), pk2(b1v[2], b1v[3]));
        }

    // ---- swap LDS plane: W2 -> W3 (all waves done reading W2) ----
    __syncthreads();
    stage_plane128(ws + W3, lds, w, l);
    __syncthreads();   // W3 resident

    // ================= layer 1: 4 ss x (G3 full-K <- LDS, phi1, G4), barrier-free =================
    v4f m1[2][4], v1[2][4];
    #pragma unroll
    for (int st = 0; st < 2; ++st)
        #pragma unroll
        for (int dt = 0; dt < 4; ++dt) { m1[st][dt] = zf; v1[st][dt] = zf; }

    for (int ss = 0; ss < 4; ++ss) {
        v4f zz[2][4], dd[2][4];
        #pragma unroll
        for (int st = 0; st < 2; ++st)
            #pragma unroll
            for (int mtl = 0; mtl < 4; ++mtl) { zz[st][mtl] = zf; dd[st][mtl] = zf; }

        __builtin_amdgcn_s_setprio(1);
        #pragma unroll
        for (int kcq = 0; kcq < 4; ++kcq) {
            #pragma unroll
            for (int mtl = 0; mtl < 4; ++mtl) {
                const char* bp = lds + (size_t)((kcq * 16 + 4 * ss + mtl) * 2) * 1024 + l * 16;
                v8s wh = *(const v8s*)bp;
                v8s wsq = *(const v8s*)(bp + 1024);
                #pragma unroll
                for (int st = 0; st < 2; ++st) {
                    zz[st][mtl] = MF(wh, m0B[st][kcq], zz[st][mtl]);
                    dd[st][mtl] = MF(wsq, v0B[st][kcq], dd[st][mtl]);
                }
            }
        }
        __builtin_amdgcn_s_setprio(0);

        // phi1 + G4 (swapped: A=phi1 row=point, B=W4 col=dim), both sets
        #pragma unroll
        for (int t2 = 0; t2 < 2; ++t2) {
            const int kc4 = 2 * ss + t2;
            float4 bbA = *(const float4*)(b1 + (4 * ss + 2 * t2) * 16 + 4 * g);
            float4 bbB = *(const float4*)(b1 + (4 * ss + 2 * t2 + 1) * 16 + 4 * g);
            v8s ph2[2], ps2[2];
            #pragma unroll
            for (int st = 0; st < 2; ++st) {
                v4f zA = zz[st][2 * t2], zB = zz[st][2 * t2 + 1];
                v4f dA = dd[st][2 * t2], dB = dd[st][2 * t2 + 1];
                float pA[4], pB[4];
                pA[0] = cosr(zA[0] + bbA.x) * __builtin_amdgcn_exp2f(dA[0]);
                pA[1] = cosr(zA[1] + bbA.y) * __builtin_amdgcn_exp2f(dA[1]);
                pA[2] = cosr(zA[2] + bbA.z) * __builtin_amdgcn_exp2f(dA[2]);
                pA[3] = cosr(zA[3] + bbA.w) * __builtin_amdgcn_exp2f(dA[3]);
                pB[0] = cosr(zB[0] + bbB.x) * __builtin_amdgcn_exp2f(dB[0]);
                pB[1] = cosr(zB[1] + bbB.y) * __builtin_amdgcn_exp2f(dB[1]);
                pB[2] = cosr(zB[2] + bbB.z) * __builtin_amdgcn_exp2f(dB[2]);
                pB[3] = cosr(zB[3] + bbB.w) * __builtin_amdgcn_exp2f(dB[3]);
                ph2[st] = mk8(pk2(pA[0], pA[1]), pk2(pA[2], pA[3]),
                              pk2(pB[0], pB[1]), pk2(pB[2], pB[3]));
                ps2[st] = mk8(pk2(pA[0]*pA[0], pA[1]*pA[1]), pk2(pA[2]*pA[2], pA[3]*pA[3]),
                              pk2(pB[0]*pB[0], pB[1]*pB[1]), pk2(pB[2]*pB[2], pB[3]*pB[3]));
            }
            __builtin_amdgcn_s_setprio(1);
            #pragma unroll
            for (int dt = 0; dt < 4; ++dt) {
                const char* wp = ws + W4 + (size_t)((kc4 * 4 + dt) * 2) * 1024 + l * 16;
                v8s wh4 = *(const v8s*)wp;
                v8s we4 = *(const v8s*)(wp + 1024);
                #pragma unroll
                for (int st = 0; st < 2; ++st) {
                    m1[st][dt] = MF(ph2[st], wh4, m1[st][dt]);
                    v1[st][dt] = MF(ps2[st], we4, v1[st][dt]);
                }
            }
            __builtin_amdgcn_s_setprio(0);
        }
    }

    // ---- epilogue per set: m1[dt] reg qi -> point 4g+qi, dim dt*16+r16; merged atomics ----
    #pragma unroll
    for (int st = 0; st < 2; ++st) {
        float s[4] = {0.f, 0.f, 0.f, 0.f};
        #pragma unroll
        for (int dt = 0; dt < 4; ++dt)
            #pragma unroll
            for (int qi = 0; qi < 4; ++qi)
                s[qi] = fmaf(m1[st][dt][qi], m1[st][dt][qi], s[qi]);
        #pragma unroll
        for (int qi = 0; qi < 4; ++qi) {
            s[qi] += __shfl_xor(s[qi], 1);
            s[qi] += __shfl_xor(s[qi], 2);
            s[qi] += __shfl_xor(s[qi], 4);
            s[qi] += __shfl_xor(s[qi], 8);
        }
        const int pbase = base + st * 16 + 4 * g;
        #pragma unroll
        for (int qi = 0; qi < 4; ++qi) {
            const int P = pbase + qi;
            if (P < NPTS) {
                const float inv_n = __builtin_amdgcn_rsqf(fmaxf(s[qi], 1e-24f));
                const int seg = xidx[P];
                const size_t ob = (size_t)seg * 64 + r16;
                #pragma unroll
                for (int dt = 0; dt < 4; ++dt) {
                    const float iv = __builtin_amdgcn_rcpf(v1[st][dt][qi]);
                    atomicAdd(sum_inv + ob + dt * 16, iv);
                    atomicAdd(sum_wm + ob + dt * 16, iv * m1[st][dt][qi] * inv_n);
                }
            }
        }
    }
}

// in-place: out0 slot holds sum_wm, out1 slot holds sum_inv
__global__ void dgp_finalize(float* __restrict__ out)
{
    const int i = blockIdx.x * blockDim.x + threadIdx.x;
    if (i < NSEG * 64) {
        const float si = out[NSEG * 64 + i];
        const float sw = out[i];
        const float ev = 1.0f / si;
        out[i] = ev * sw;
        out[NSEG * 64 + i] = ev;
    }
}

extern "C" void kernel_launch(void* const* d_in, const int* in_sizes, int n_in,
                              void* d_out, int out_size, void* d_ws, size_t ws_size,
                              hipStream_t stream)
{
    const float* x    = (const float*)d_in[0];
    const float* Om0  = (const float*)d_in[1];
    const float* b0   = (const float*)d_in[2];
    const float* Wm0  = (const float*)d_in[3];
    const float* Wlv0 = (const float*)d_in[4];
    const float* Om1  = (const float*)d_in[5];
    const float* b1   = (const float*)d_in[6];
    const float* Wm1  = (const float*)d_in[7];
    const float* Wlv1 = (const float*)d_in[8];
    const int*   xidx = (const int*)d_in[9];

    float* out = (float*)d_out;
    char*  wsc = (char*)d_ws;

    hipMemsetAsync(d_out, 0, (size_t)out_size * sizeof(float), stream);

    dgp_prep<<<128, 256, 0, stream>>>(Om0, Wm0, Wlv0, Om1, Wm1, Wlv1, b0, b1, wsc);

    float* sum_wm  = out;               // -> output 0
    float* sum_inv = out + NSEG * 64;   // -> output 1 (embed_vars)
    const int nblk = (NPTS + 255) / 256;  // 1954 blocks x 512 threads (8 waves x 32 pts)
    dgp_main<<<nblk, 512, 0, stream>>>(x, xidx,
                                       (const float*)(wsc + B0P), (const float*)(wsc + B1P),
                                       (const char*)wsc, sum_wm, sum_inv);

    dgp_finalize<<<(NSEG * 64 + 255) / 256, 256, 0, stream>>>(out);
}

// Round 12
// 350.413 us; speedup vs baseline: 1.1914x; 1.1914x over previous
//
#include <hip/hip_runtime.h>
#include <hip/hip_bf16.h>
#include <math.h>

#define NSEG 25000
#define NPTS 500000
#define S_RFF 0.08838834764831845f      // sqrt(2/256)
#define INV2PI 0.15915494309189535f     // 1/(2*pi)
#define C_EXP2 (-0.7213475204444817f)   // -0.5*log2(e)

typedef __attribute__((ext_vector_type(8))) short v8s;
typedef __attribute__((ext_vector_type(4))) float v4f;

#define MF(a,b,c) __builtin_amdgcn_mfma_f32_16x16x32_bf16(a,b,c,0,0,0)

// ---- d_ws plane offsets (fragment order; constants folded at prep) ----
#define W1 0          // (Om0/2pi)^T [mt 16][kcg 2][pl 2(hi,lo)] x 1KB = 64KB  (no pi)
#define W2 65536      // (S*Wm0)^T   [kc 8][mt 8][pl 2(hi, S^2*E)] x 1KB = 128KB (pi)
#define W3 196608     // (Om1/2pi)^T [kc 4][mt 16][pl 2(hi, C*Om1^2)] x 1KB = 128KB (pi)
#define W4 327680     // (S*Wm1)     [kc 8][dt 4][pl 2(hi, S^2*E)] x 1KB = 64KB (pi, B-frag)
#define B0P 393216    // b0/2pi, 256 floats
#define B1P 394240    // b1/2pi, 256 floats
// total ~386KB, fully L2-resident

__device__ __forceinline__ ushort bf16_rne(float f) {
    uint u = __builtin_bit_cast(uint, f);
    u += 0x7fffu + ((u >> 16) & 1u);
    return (ushort)(u >> 16);
}
__device__ __forceinline__ float bf16f(ushort h) {
    uint u = ((uint)h) << 16;
    return __builtin_bit_cast(float, u);
}
__device__ __forceinline__ uint pk2(float a, float b) {
    __hip_bfloat162 h = __float22bfloat162_rn(make_float2(a, b));
    union { __hip_bfloat162 h; uint u; } c; c.h = h; return c.u;
}
__device__ __forceinline__ v8s mk8(uint a, uint b, uint c, uint d) {
    union { uint u[4]; v8s v; } x; x.u[0]=a; x.u[1]=b; x.u[2]=c; x.u[3]=d; return x.v;
}
__device__ __forceinline__ void unpk2(uint u, float& a, float& b) {
    a = __builtin_bit_cast(float, u << 16);
    b = __builtin_bit_cast(float, u & 0xffff0000u);
}
// cos with argument in revolutions: v_fract + v_cos (2 instructions)
__device__ __forceinline__ float cosr(float x) {
    return __builtin_amdgcn_cosf(__builtin_amdgcn_fractf(x));
}

// slot position for k-permuted frags: far side provides k = 4g+j (j<4) / 16+4g+(j-4)
__device__ __forceinline__ int pi_el(int k32, int row) {
    int gk, j;
    if (k32 < 16) { gk = k32 >> 2; j = k32 & 3; }
    else          { gk = (k32 - 16) >> 2; j = 4 + ((k32 - 16) & 3); }
    return (gk * 16 + row) * 8 + j;
}

// ---------- prep: weights -> fragment planes with folded constants (unchanged) ----------
__global__ void dgp_prep(const float* __restrict__ Om0, const float* __restrict__ Wm0,
                         const float* __restrict__ Wlv0, const float* __restrict__ Om1,
                         const float* __restrict__ Wm1, const float* __restrict__ Wlv1,
                         const float* __restrict__ b0, const float* __restrict__ b1,
                         char* __restrict__ ws)
{
    const int idx = blockIdx.x * 256 + threadIdx.x;   // 0..32767
    if (idx < 16384) {   // W1: (Om0/2pi) hi/lo (3-term G1 kept)
        int k = idx >> 8, c = idx & 255;
        int kcg = k >> 5, k32 = k & 31, mt = c >> 4, row = c & 15;
        int el = ((k32 >> 3) * 16 + row) * 8 + (k32 & 7);
        float v = Om0[idx] * INV2PI;
        ushort hi = bf16_rne(v), lo = bf16_rne(v - bf16f(hi));
        ushort* p = (ushort*)(ws + W1);
        int t0 = (mt * 2 + kcg) * 2;
        p[(size_t)t0 * 512 + el] = hi;
        p[(size_t)(t0 + 1) * 512 + el] = lo;
    }
    {   // W2: S*Wm0 + S^2*exp(Wlv0), single-term, pi
        int k = idx >> 7, n = idx & 127;
        int kc = k >> 5, k32 = k & 31, mt = n >> 4, row = n & 15;
        int el = pi_el(k32, row);
        ushort* p = (ushort*)(ws + W2);
        int t0 = (kc * 8 + mt) * 2;
        p[(size_t)t0 * 512 + el] = bf16_rne(S_RFF * Wm0[idx]);
        p[(size_t)(t0 + 1) * 512 + el] = bf16_rne(S_RFF * S_RFF * expf(Wlv0[idx]));
    }
    {   // W3: Om1/2pi + (-0.5*log2e)*Om1^2, single-term, pi
        int k = idx >> 8, c = idx & 255;
        int kc = k >> 5, k32 = k & 31, mt = c >> 4, row = c & 15;
        int el = pi_el(k32, row);
        float v = Om1[idx];
        ushort* p = (ushort*)(ws + W3);
        int t0 = (kc * 16 + mt) * 2;
        p[(size_t)t0 * 512 + el] = bf16_rne(v * INV2PI);
        p[(size_t)(t0 + 1) * 512 + el] = bf16_rne(C_EXP2 * v * v);
    }
    if (idx < 16384) {   // W4: S*Wm1 + S^2*exp(Wlv1), pi (B-frag)
        int k = idx >> 6, d = idx & 63;
        int kc = k >> 5, k32 = k & 31, dt = d >> 4, row = d & 15;
        int el = pi_el(k32, row);
        ushort* p = (ushort*)(ws + W4);
        int t0 = (kc * 4 + dt) * 2;
        p[(size_t)t0 * 512 + el] = bf16_rne(S_RFF * Wm1[idx]);
        p[(size_t)(t0 + 1) * 512 + el] = bf16_rne(S_RFF * S_RFF * expf(Wlv1[idx]));
    }
    if (idx < 256) ((float*)(ws + B0P))[idx] = b0[idx] * INV2PI;
    if (idx < 256) ((float*)(ws + B1P))[idx] = b1[idx] * INV2PI;
}

// ---------- weight-chunk staging (global -> LDS, linear, 16B/lane, 4 waves) ----------
typedef __attribute__((address_space(1))) const unsigned int g_u32;
typedef __attribute__((address_space(3))) unsigned int l_u32;

template <int NKB>
__device__ __forceinline__ void stage_kb(const char* gsrc, char* dst, int w, int l) {
    #pragma unroll
    for (int i = 0; i < (NKB + 3) / 4; ++i) {
        const int idx = i * 4 + w;
        if (idx < NKB)
            __builtin_amdgcn_global_load_lds((g_u32*)(gsrc + idx * 1024 + l * 16),
                                             (l_u32*)(dst + idx * 1024), 16, 0, 0);
    }
}

// ---------- fused main: 4 waves x 32 pts (2 B-sets); FULLY UNROLLED phases ----------
__global__ __launch_bounds__(256, 2)
void dgp_main(const float* __restrict__ x, const int* __restrict__ xidx,
              const float* __restrict__ b0, const float* __restrict__ b1,
              const char* __restrict__ ws,
              float* __restrict__ sum_wm, float* __restrict__ sum_inv)
{
    __shared__ __attribute__((aligned(16))) char lds[32768];   // 2 x 16KB ring
    const int t = threadIdx.x, l = t & 63, w = t >> 6;          // w 0..3
    const int r16 = l & 15, g = l >> 4;
    const int base = blockIdx.x * 128 + w * 32;

    const v4f zf = {0.f, 0.f, 0.f, 0.f};

    // ---- x B-frags (hi/lo, 2 sets x 2 K-chunks) ----
    v8s xh[2][2], xl[2][2];
    #pragma unroll
    for (int st = 0; st < 2; ++st) {
        const int pc = min(base + st * 16 + r16, NPTS - 1);
        #pragma unroll
        for (int kcg = 0; kcg < 2; ++kcg) {
            const float* xp = x + (size_t)pc * 64 + kcg * 32 + g * 8;
            float4 a = *(const float4*)xp;
            float4 b = *(const float4*)(xp + 4);
            uint h0 = pk2(a.x, a.y), h1 = pk2(a.z, a.w), h2 = pk2(b.x, b.y), h3 = pk2(b.z, b.w);
            float q0,q1,q2,q3,q4,q5,q6,q7;
            unpk2(h0,q0,q1); unpk2(h1,q2,q3); unpk2(h2,q4,q5); unpk2(h3,q6,q7);
            xh[st][kcg] = mk8(h0, h1, h2, h3);
            xl[st][kcg] = mk8(pk2(a.x-q0, a.y-q1), pk2(a.z-q2, a.w-q3),
                              pk2(b.x-q4, b.y-q5), pk2(b.z-q6, b.w-q7));
        }
    }

    v4f am[2][8], av[2][8];
    #pragma unroll
    for (int st = 0; st < 2; ++st)
        #pragma unroll
        for (int nt = 0; nt < 8; ++nt) { am[st][nt] = zf; av[st][nt] = zf; }

    v4f zc[2][2] = {{zf, zf}, {zf, zf}};

    // G1: accumulate z'^T pair for tile-pair kc into z[set][tt] (3-term split product)
    auto G1 = [&](int kc, v4f z[2][2]) {
        #pragma unroll
        for (int tt = 0; tt < 2; ++tt) {
            const int mt = 2 * kc + tt;
            #pragma unroll
            for (int kcg = 0; kcg < 2; ++kcg) {
                const char* wp = ws + W1 + (size_t)((mt * 2 + kcg) * 2) * 1024 + l * 16;
                v8s ah = *(const v8s*)wp;
                v8s al = *(const v8s*)(wp + 1024);
                #pragma unroll
                for (int st = 0; st < 2; ++st) {
                    v4f a = z[st][tt];
                    a = MF(ah, xh[st][kcg], a);
                    a = MF(al, xh[st][kcg], a);
                    a = MF(ah, xl[st][kcg], a);
                    z[st][tt] = a;
                }
            }
        }
    };

    // ================= layer 0: pipelined phases, FULLY UNROLLED =================
    stage_kb<16>(ws + W2, lds, w, l);
    G1(0, zc);
    __syncthreads();

    auto phase0 = [&](int kc, bool dn) {
        v4f zn[2][2] = {{zf, zf}, {zf, zf}};
        if (dn) G1(kc + 1, zn);

        float4 bbA = *(const float4*)(b0 + (2 * kc) * 16 + 4 * g);
        float4 bbB = *(const float4*)(b0 + (2 * kc + 1) * 16 + 4 * g);
        v8s ph[2], psq[2];
        #pragma unroll
        for (int st = 0; st < 2; ++st) {
            float pA[4], pB[4];
            pA[0] = cosr(zc[st][0][0] + bbA.x);
            pA[1] = cosr(zc[st][0][1] + bbA.y);
            pA[2] = cosr(zc[st][0][2] + bbA.z);
            pA[3] = cosr(zc[st][0][3] + bbA.w);
            pB[0] = cosr(zc[st][1][0] + bbB.x);
            pB[1] = cosr(zc[st][1][1] + bbB.y);
            pB[2] = cosr(zc[st][1][2] + bbB.z);
            pB[3] = cosr(zc[st][1][3] + bbB.w);
            ph[st]  = mk8(pk2(pA[0], pA[1]), pk2(pA[2], pA[3]),
                          pk2(pB[0], pB[1]), pk2(pB[2], pB[3]));
            psq[st] = mk8(pk2(pA[0]*pA[0], pA[1]*pA[1]), pk2(pA[2]*pA[2], pA[3]*pA[3]),
                          pk2(pB[0]*pB[0], pB[1]*pB[1]), pk2(pB[2]*pB[2], pB[3]*pB[3]));
        }

        __builtin_amdgcn_s_setprio(1);
        #pragma unroll
        for (int nt = 0; nt < 8; ++nt) {
            const char* bp = lds + (kc & 1) * 16384 + nt * 2048 + l * 16;
            v8s wh = *(const v8s*)bp;
            v8s we = *(const v8s*)(bp + 1024);
            #pragma unroll
            for (int st = 0; st < 2; ++st) {
                am[st][nt] = MF(wh, ph[st], am[st][nt]);
                av[st][nt] = MF(we, psq[st], av[st][nt]);
            }
        }
        __builtin_amdgcn_s_setprio(0);
        #pragma unroll
        for (int st = 0; st < 2; ++st) { zc[st][0] = zn[st][0]; zc[st][1] = zn[st][1]; }
    };

    #pragma unroll
    for (int kc = 0; kc < 7; ++kc) {
        char* nxt = lds + ((kc + 1) & 1) * 16384;
        stage_kb<16>(ws + W2 + (size_t)(kc + 1) * 16384, nxt, w, l);
        phase0(kc, true);
        __syncthreads();
    }
    {   // kc = 7: cross-over staging of layer-1 chunk 0 (ss=0, kch=0)
        char* nxt = lds;
        stage_kb<8>(ws + W3 + (size_t)(0 * 16 + 0) * 2048, nxt, w, l);
        stage_kb<8>(ws + W3 + (size_t)(1 * 16 + 0) * 2048, nxt + 8192, w, l);
        phase0(7, false);
        __syncthreads();
    }

    // ---- transition: m0/v0 accs -> B-frags (in-register pack) ----
    v8s m0B[2][4], v0B[2][4];
    #pragma unroll
    for (int st = 0; st < 2; ++st)
        #pragma unroll
        for (int kd = 0; kd < 4; ++kd) {
            v4f a0 = am[st][2 * kd], a1 = am[st][2 * kd + 1];
            v4f b0v = av[st][2 * kd], b1v = av[st][2 * kd + 1];
            m0B[st][kd] = mk8(pk2(a0[0], a0[1]), pk2(a0[2], a0[3]),
                              pk2(a1[0], a1[1]), pk2(a1[2], a1[3]));
            v0B[st][kd] = mk8(pk2(b0v[0], b0v[1]), pk2(b0v[2], b0v[3]),
                              pk2(b1v[0], b1v[1]), pk2(b1v[2], b1v[3]));
        }

    // ================= layer 1: 8 phases (4 ss x 2 kch), FULLY UNROLLED =================
    v4f m1[2][4], v1[2][4];
    #pragma unroll
    for (int st = 0; st < 2; ++st)
        #pragma unroll
        for (int dt = 0; dt < 4; ++dt) { m1[st][dt] = zf; v1[st][dt] = zf; }

    #pragma unroll
    for (int ss = 0; ss < 4; ++ss) {
        v4f zz[2][4], dd[2][4];
        #pragma unroll
        for (int st = 0; st < 2; ++st)
            #pragma unroll
            for (int mtl = 0; mtl < 4; ++mtl) { zz[st][mtl] = zf; dd[st][mtl] = zf; }

        #pragma unroll
        for (int kch = 0; kch < 2; ++kch) {
            const int p = ss * 2 + kch;
            const char* buf = lds + (p & 1) * 16384;
            if (p < 7) {
                const int c = p + 1;
                const int s2 = c >> 1, k2 = c & 1;
                char* dst = lds + ((p + 1) & 1) * 16384;
                stage_kb<8>(ws + W3 + (size_t)((2 * k2) * 16 + 4 * s2) * 2048, dst, w, l);
                stage_kb<8>(ws + W3 + (size_t)((2 * k2 + 1) * 16 + 4 * s2) * 2048, dst + 8192, w, l);
            }
            __builtin_amdgcn_s_setprio(1);
            #pragma unroll
            for (int q = 0; q < 2; ++q) {
                const int kcq = 2 * kch + q;
                #pragma unroll
                for (int mtl = 0; mtl < 4; ++mtl) {
                    const char* bp = buf + q * 8192 + mtl * 2048 + l * 16;
                    v8s wh = *(const v8s*)bp;
                    v8s wsq = *(const v8s*)(bp + 1024);
                    #pragma unroll
                    for (int st = 0; st < 2; ++st) {
                        zz[st][mtl] = MF(wh, m0B[st][kcq], zz[st][mtl]);
                        dd[st][mtl] = MF(wsq, v0B[st][kcq], dd[st][mtl]);
                    }
                }
            }
            __builtin_amdgcn_s_setprio(0);
            if (kch == 1) {
                // phi1 + G4 (swapped: A=phi1 row=point, B=W4 col=dim), both sets
                #pragma unroll
                for (int t2 = 0; t2 < 2; ++t2) {
                    const int kc4 = 2 * ss + t2;
                    float4 bbA = *(const float4*)(b1 + (4 * ss + 2 * t2) * 16 + 4 * g);
                    float4 bbB = *(const float4*)(b1 + (4 * ss + 2 * t2 + 1) * 16 + 4 * g);
                    v8s ph2[2], ps2[2];
                    #pragma unroll
                    for (int st = 0; st < 2; ++st) {
                        v4f zA = zz[st][2 * t2], zB = zz[st][2 * t2 + 1];
                        v4f dA = dd[st][2 * t2], dB = dd[st][2 * t2 + 1];
                        float pA[4], pB[4];
                        pA[0] = cosr(zA[0] + bbA.x) * __builtin_amdgcn_exp2f(dA[0]);
                        pA[1] = cosr(zA[1] + bbA.y) * __builtin_amdgcn_exp2f(dA[1]);
                        pA[2] = cosr(zA[2] + bbA.z) * __builtin_amdgcn_exp2f(dA[2]);
                        pA[3] = cosr(zA[3] + bbA.w) * __builtin_amdgcn_exp2f(dA[3]);
                        pB[0] = cosr(zB[0] + bbB.x) * __builtin_amdgcn_exp2f(dB[0]);
                        pB[1] = cosr(zB[1] + bbB.y) * __builtin_amdgcn_exp2f(dB[1]);
                        pB[2] = cosr(zB[2] + bbB.z) * __builtin_amdgcn_exp2f(dB[2]);
                        pB[3] = cosr(zB[3] + bbB.w) * __builtin_amdgcn_exp2f(dB[3]);
                        ph2[st] = mk8(pk2(pA[0], pA[1]), pk2(pA[2], pA[3]),
                                      pk2(pB[0], pB[1]), pk2(pB[2], pB[3]));
                        ps2[st] = mk8(pk2(pA[0]*pA[0], pA[1]*pA[1]), pk2(pA[2]*pA[2], pA[3]*pA[3]),
                                      pk2(pB[0]*pB[0], pB[1]*pB[1]), pk2(pB[2]*pB[2], pB[3]*pB[3]));
                    }
                    __builtin_amdgcn_s_setprio(1);
                    #pragma unroll
                    for (int dt = 0; dt < 4; ++dt) {
                        const char* wp = ws + W4 + (size_t)((kc4 * 4 + dt) * 2) * 1024 + l * 16;
                        v8s wh4 = *(const v8s*)wp;
                        v8s we4 = *(const v8s*)(wp + 1024);
                        #pragma unroll
                        for (int st = 0; st < 2; ++st) {
                            m1[st][dt] = MF(ph2[st], wh4, m1[st][dt]);
                            v1[st][dt] = MF(ps2[st], we4, v1[st][dt]);
                        }
                    }
                    __builtin_amdgcn_s_setprio(0);
                }
            }
            __syncthreads();
        }
    }

    // ---- epilogue per set: m1[dt] reg qi -> point 4g+qi, dim dt*16+r16; merged atomics ----
    #pragma unroll
    for (int st = 0; st < 2; ++st) {
        float s[4] = {0.f, 0.f, 0.f, 0.f};
        #pragma unroll
        for (int dt = 0; dt < 4; ++dt)
            #pragma unroll
            for (int qi = 0; qi < 4; ++qi)
                s[qi] = fmaf(m1[st][dt][qi], m1[st][dt][qi], s[qi]);
        #pragma unroll
        for (int qi = 0; qi < 4; ++qi) {
            s[qi] += __shfl_xor(s[qi], 1);
            s[qi] += __shfl_xor(s[qi], 2);
            s[qi] += __shfl_xor(s[qi], 4);
            s[qi] += __shfl_xor(s[qi], 8);
        }
        const int pbase = base + st * 16 + 4 * g;
        #pragma unroll
        for (int qi = 0; qi < 4; ++qi) {
            const int P = pbase + qi;
            if (P < NPTS) {
                const float inv_n = __builtin_amdgcn_rsqf(fmaxf(s[qi], 1e-24f));
                const int seg = xidx[P];
                const size_t ob = (size_t)seg * 64 + r16;
                #pragma unroll
                for (int dt = 0; dt < 4; ++dt) {
                    const float iv = __builtin_amdgcn_rcpf(v1[st][dt][qi]);
                    atomicAdd(sum_inv + ob + dt * 16, iv);
                    atomicAdd(sum_wm + ob + dt * 16, iv * m1[st][dt][qi] * inv_n);
                }
            }
        }
    }
}

// in-place: out0 slot holds sum_wm, out1 slot holds sum_inv
__global__ void dgp_finalize(float* __restrict__ out)
{
    const int i = blockIdx.x * blockDim.x + threadIdx.x;
    if (i < NSEG * 64) {
        const float si = out[NSEG * 64 + i];
        const float sw = out[i];
        const float ev = 1.0f / si;
        out[i] = ev * sw;
        out[NSEG * 64 + i] = ev;
    }
}

extern "C" void kernel_launch(void* const* d_in, const int* in_sizes, int n_in,
                              void* d_out, int out_size, void* d_ws, size_t ws_size,
                              hipStream_t stream)
{
    const float* x    = (const float*)d_in[0];
    const float* Om0  = (const float*)d_in[1];
    const float* b0   = (const float*)d_in[2];
    const float* Wm0  = (const float*)d_in[3];
    const float* Wlv0 = (const float*)d_in[4];
    const float* Om1  = (const float*)d_in[5];
    const float* b1   = (const float*)d_in[6];
    const float* Wm1  = (const float*)d_in[7];
    const float* Wlv1 = (const float*)d_in[8];
    const int*   xidx = (const int*)d_in[9];

    float* out = (float*)d_out;
    char*  wsc = (char*)d_ws;

    hipMemsetAsync(d_out, 0, (size_t)out_size * sizeof(float), stream);

    dgp_prep<<<128, 256, 0, stream>>>(Om0, Wm0, Wlv0, Om1, Wm1, Wlv1, b0, b1, wsc);

    float* sum_wm  = out;               // -> output 0
    float* sum_inv = out + NSEG * 64;   // -> output 1 (embed_vars)
    const int nblk = (NPTS + 127) / 128;  // 3907 blocks x 256 threads (4 waves x 32 pts)
    dgp_main<<<nblk, 256, 0, stream>>>(x, xidx,
                                       (const float*)(wsc + B0P), (const float*)(wsc + B1P),
                                       (const char*)wsc, sum_wm, sum_inv);

    dgp_finalize<<<(NSEG * 64 + 255) / 256, 256, 0, stream>>>(out);
}